// Round 1
// baseline (225.466 us; speedup 1.0000x reference)
//
#include <hip/hip_runtime.h>
#include <math.h>

namespace {

constexpr int B = 64, E = 256, H = 512, V = 50257, KV = 2048;

typedef __bf16 bf16x8 __attribute__((ext_vector_type(8)));
typedef float f32x4 __attribute__((ext_vector_type(4)));

__device__ __forceinline__ float fast_tanh(float x) {
  float e = __expf(2.f * x);
  return 1.f - 2.f / (e + 1.f);
}
__device__ __forceinline__ float sigmoidf(float x) {
  return 1.f / (1.f + __expf(-x));
}
__device__ __forceinline__ f32x4 mfma16(bf16x8 a, bf16x8 b, f32x4 c) {
  return __builtin_amdgcn_mfma_f32_16x16x32_bf16(a, b, c, 0, 0, 0);
}

// ---------------- LSTM gates: gates[j][b] = b_ih[j]+b_hh[j] + x[b].W_ih[j] + h0[b].W_hh[j]
__global__ __launch_bounds__(256) void k_gates(const int* __restrict__ inp,
    const float* __restrict__ h0, const float* __restrict__ emb,
    const float* __restrict__ W_ih, const float* __restrict__ b_ih,
    const float* __restrict__ W_hh, const float* __restrict__ b_hh,
    float* __restrict__ gates) {
  int b = threadIdx.x & 63;
  int j = blockIdx.x * 4 + (threadIdx.x >> 6);
  j = __builtin_amdgcn_readfirstlane(j);
  int row = inp[b];
  const float* xr = emb + (long)row * E;
  const float* wi = W_ih + (long)j * E;
  const float* hr = h0 + b * H;
  const float* wh = W_hh + (long)j * H;
  float acc = b_ih[j] + b_hh[j];
#pragma unroll 8
  for (int t = 0; t < E / 4; ++t) {
    float4 x4 = ((const float4*)xr)[t];
    float4 w4 = ((const float4*)wi)[t];
    acc += x4.x * w4.x + x4.y * w4.y + x4.z * w4.z + x4.w * w4.w;
  }
#pragma unroll 8
  for (int t = 0; t < H / 4; ++t) {
    float4 h4 = ((const float4*)hr)[t];
    float4 w4 = ((const float4*)wh)[t];
    acc += h4.x * w4.x + h4.y * w4.y + h4.z * w4.z + h4.w * w4.w;
  }
  gates[j * B + b] = acc;
}

// ---------------- LSTM elementwise: h_t, c_t
__global__ __launch_bounds__(256) void k_lstm(const float* __restrict__ gates,
    const float* __restrict__ c0, float* __restrict__ out_h, float* __restrict__ out_c) {
  int i = blockIdx.x * 256 + threadIdx.x;  // 32768 = B*H
  int b = i >> 9, hh = i & 511;
  float gi = gates[(hh)*B + b];
  float gf = gates[(hh + 512) * B + b];
  float gg = gates[(hh + 1024) * B + b];
  float go = gates[(hh + 1536) * B + b];
  float c = sigmoidf(gf) * c0[i] + sigmoidf(gi) * fast_tanh(gg);
  float h = sigmoidf(go) * fast_tanh(c);
  out_h[i] = h;
  out_c[i] = c;
}

// ---------------- Ah[b][e] = b1[e] + h_t[b] . W1[e][0:512]
__global__ __launch_bounds__(256) void k_ah(const float* __restrict__ h_t,
    const float* __restrict__ W1, const float* __restrict__ b1, float* __restrict__ Ah) {
  int b = threadIdx.x & 63;
  int e = blockIdx.x * 4 + (threadIdx.x >> 6);
  e = __builtin_amdgcn_readfirstlane(e);
  const float* hr = h_t + b * H;
  const float* wr = W1 + (long)e * (E + H);
  float acc = b1[e];
#pragma unroll 8
  for (int t = 0; t < H / 4; ++t) {
    float4 h4 = ((const float4*)hr)[t];
    float4 w4 = ((const float4*)wr)[t];
    acc += h4.x * w4.x + h4.y * w4.y + h4.z * w4.z + h4.w * w4.w;
  }
  Ah[b * E + e] = acc;
}

// ---------------- Kp[kv][e] = k[kv] . W1[e][512:768]   (tiled 64x64, K=256)
__global__ __launch_bounds__(256) void k_kp(const float* __restrict__ k,
    const float* __restrict__ W1, float* __restrict__ Kp) {
  __shared__ float ks_[64][257];
  int kv0 = blockIdx.x * 64;
  int e0 = blockIdx.y * 64;
  int t = threadIdx.x;
  for (int i = 0; i < 16; ++i) {
    int idx = i * 256 + t;  // 4096 float4 chunks
    int rr = idx >> 6, cc = (idx & 63) * 4;
    float4 v = *(const float4*)(k + (kv0 + rr) * E + cc);
    ks_[rr][cc] = v.x; ks_[rr][cc + 1] = v.y; ks_[rr][cc + 2] = v.z; ks_[rr][cc + 3] = v.w;
  }
  __syncthreads();
  int r0 = (t >> 4);        // rows r0, r0+16, r0+32, r0+48
  int c0 = (t & 15) * 4;    // 4 consecutive e
  float acc[4][4] = {};
  const float* w0 = W1 + (long)(e0 + c0) * (E + H) + H;
  for (int kk = 0; kk < 256; kk += 4) {
    float4 w[4];
#pragma unroll
    for (int c = 0; c < 4; ++c) w[c] = *(const float4*)(w0 + (long)c * (E + H) + kk);
#pragma unroll
    for (int q = 0; q < 4; ++q) {
#pragma unroll
      for (int r = 0; r < 4; ++r) {
        float kvv = ks_[r0 + 16 * r][kk + q];
#pragma unroll
        for (int c = 0; c < 4; ++c) acc[r][c] += kvv * ((const float*)&w[c])[q];
      }
    }
  }
  for (int r = 0; r < 4; ++r)
    for (int c = 0; c < 4; ++c)
      Kp[(kv0 + r0 + 16 * r) * E + e0 + c0 + c] = acc[r][c];
}

// ---------------- pack W2^T into bf16 MFMA-B-fragment layout
__global__ __launch_bounds__(256) void k_packw2(const float* __restrict__ W2, __bf16* __restrict__ W2p) {
  int idx = blockIdx.x * 256 + threadIdx.x;  // 65536
  int k = idx >> 8, n = idx & 255;
  W2p[((k >> 3) * 256 + n) * 8 + (k & 7)] = (__bf16)W2[n * 256 + k];
}

// ---------------- pack h_t into bf16 MFMA-A-fragment layout
__global__ __launch_bounds__(256) void k_packh(const float* __restrict__ h_t, __bf16* __restrict__ hp) {
  int idx = blockIdx.x * 256 + threadIdx.x;  // 32768
  int k = idx & 511, m = idx >> 9;
  hp[((k >> 3) * 64 + m) * 8 + (k & 7)] = (__bf16)h_t[m * 512 + k];
}

// ---------------- attention core: per block 64 kv rows for one b.
// u1 = tanh(Ah[b]+Kp[kv]) staged to LDS (bf16, XOR-swizzled); u2 = tanh(u1@W2^T + b2);
// scores[b][kv] = u2 . w3 + b3
__global__ __launch_bounds__(256) void k_attn(const float* __restrict__ Ah,
    const float* __restrict__ Kp, const __bf16* __restrict__ W2p,
    const float* __restrict__ b2, const float* __restrict__ W3, const float* __restrict__ b3,
    float* __restrict__ scores) {
  __shared__ __align__(16) unsigned char lds_[64 * 256 * 2];
  int tid = threadIdx.x;
  int blk = blockIdx.x;             // 2048
  int b = blk >> 5;
  int kv0 = (blk & 31) * 64;
  for (int i = 0; i < 8; ++i) {
    int idx = i * 256 + tid;        // 2048 chunks of 8
    int row = idx >> 5;
    int k0 = (idx & 31) * 8;
    const float* ap = Ah + b * E + k0;
    const float* kp = Kp + (kv0 + row) * E + k0;
    float4 a0 = *(const float4*)ap;
    float4 a1 = *(const float4*)(ap + 4);
    float4 p0 = *(const float4*)kp;
    float4 p1 = *(const float4*)(kp + 4);
    bf16x8 u;
    u[0] = (__bf16)fast_tanh(a0.x + p0.x);
    u[1] = (__bf16)fast_tanh(a0.y + p0.y);
    u[2] = (__bf16)fast_tanh(a0.z + p0.z);
    u[3] = (__bf16)fast_tanh(a0.w + p0.w);
    u[4] = (__bf16)fast_tanh(a1.x + p1.x);
    u[5] = (__bf16)fast_tanh(a1.y + p1.y);
    u[6] = (__bf16)fast_tanh(a1.z + p1.z);
    u[7] = (__bf16)fast_tanh(a1.w + p1.w);
    int byte = (row * 512 + k0 * 2) ^ ((row & 7) << 4);
    *(bf16x8*)(lds_ + byte) = u;
  }
  __syncthreads();
  int l = tid & 63, wc = tid >> 6;  // 4 waves, each owns a 64-col chunk
  int lr = l & 15, lg = l >> 4;
  float b2v[4], w3v[4];
#pragma unroll
  for (int nf = 0; nf < 4; ++nf) {
    int col = wc * 64 + nf * 16 + lr;
    b2v[nf] = b2[col];
    w3v[nf] = W3[col];
  }
  f32x4 acc[4][4] = {};
  for (int ks = 0; ks < 8; ++ks) {
    bf16x8 a[4], bf[4];
#pragma unroll
    for (int mf = 0; mf < 4; ++mf) {
      int row = mf * 16 + lr;
      int byte = (row * 512 + (ks * 32 + lg * 8) * 2) ^ ((row & 7) << 4);
      a[mf] = *(const bf16x8*)(lds_ + byte);
    }
#pragma unroll
    for (int nf = 0; nf < 4; ++nf) {
      int col = wc * 64 + nf * 16 + lr;
      bf[nf] = *(const bf16x8*)(W2p + ((ks * 4 + lg) * 256 + col) * 8);
    }
#pragma unroll
    for (int mf = 0; mf < 4; ++mf)
#pragma unroll
      for (int nf = 0; nf < 4; ++nf)
        acc[mf][nf] = mfma16(a[mf], bf[nf], acc[mf][nf]);
  }
  // epilogue: u2=tanh(acc+b2), dot with w3, reduce over cols
  float p[4][4];
#pragma unroll
  for (int mf = 0; mf < 4; ++mf)
#pragma unroll
    for (int r = 0; r < 4; ++r) p[mf][r] = 0.f;
#pragma unroll
  for (int mf = 0; mf < 4; ++mf)
#pragma unroll
    for (int nf = 0; nf < 4; ++nf)
#pragma unroll
      for (int r = 0; r < 4; ++r) {
        float u2 = fast_tanh(acc[mf][nf][r] + b2v[nf]);
        p[mf][r] += u2 * w3v[nf];
      }
#pragma unroll
  for (int off = 1; off < 16; off <<= 1)
#pragma unroll
    for (int mf = 0; mf < 4; ++mf)
#pragma unroll
      for (int r = 0; r < 4; ++r) p[mf][r] += __shfl_xor(p[mf][r], off);
  __syncthreads();
  float* red = (float*)lds_;  // [64][4]
  if (lr == 0) {
#pragma unroll
    for (int mf = 0; mf < 4; ++mf)
#pragma unroll
      for (int r = 0; r < 4; ++r) red[(mf * 16 + lg * 4 + r) * 4 + wc] = p[mf][r];
  }
  __syncthreads();
  if (tid < 64) {
    float s = red[tid * 4 + 0] + red[tid * 4 + 1] + red[tid * 4 + 2] + red[tid * 4 + 3] + b3[0];
    scores[b * KV + kv0 + tid] = s;
  }
}

// ---------------- output projection: o[m][v] = h_t[m].W_out[v] + b_out[v] (+score), MFMA bf16
__global__ __launch_bounds__(256) void k_out(const __bf16* __restrict__ hp,
    const float* __restrict__ W_out, const float* __restrict__ b_out,
    const float* __restrict__ scores, float* __restrict__ o) {
  int tid = threadIdx.x;
  int l = tid & 63, wn = tid >> 6;
  int lr = l & 15, lg = l >> 4;
  int col = blockIdx.x * 64 + wn * 16 + lr;
  int colc = col < V ? col : V - 1;
  const float* wr = W_out + (long)colc * H;
  f32x4 acc[4] = {};
  for (int ks = 0; ks < 16; ++ks) {
    bf16x8 a[4];
#pragma unroll
    for (int mf = 0; mf < 4; ++mf)
      a[mf] = *(const bf16x8*)(hp + ((ks * 4 + lg) * 64 + mf * 16 + lr) * 8);
    const float* wp = wr + ks * 32 + lg * 8;
    float4 w0 = *(const float4*)wp;
    float4 w1 = *(const float4*)(wp + 4);
    bf16x8 bf;
    bf[0] = (__bf16)w0.x; bf[1] = (__bf16)w0.y; bf[2] = (__bf16)w0.z; bf[3] = (__bf16)w0.w;
    bf[4] = (__bf16)w1.x; bf[5] = (__bf16)w1.y; bf[6] = (__bf16)w1.z; bf[7] = (__bf16)w1.w;
#pragma unroll
    for (int mf = 0; mf < 4; ++mf) acc[mf] = mfma16(a[mf], bf, acc[mf]);
  }
  if (col < V) {
    float bo = b_out[col];
    bool has = col >= (V - KV);
    int scix = col - (V - KV);
#pragma unroll
    for (int mf = 0; mf < 4; ++mf)
#pragma unroll
      for (int r = 0; r < 4; ++r) {
        int m = mf * 16 + lg * 4 + r;
        float v = acc[mf][r] + bo;
        if (has) v += scores[m * KV + scix];
        o[(long)m * V + col] = v;
      }
  }
}

// ---------------- per-row logsumexp (online)
__global__ __launch_bounds__(512) void k_lse(const float* __restrict__ o, float* __restrict__ logZ) {
  int r = blockIdx.x;
  const float* row = o + (long)r * V;
  float m = -__builtin_inff(), s = 0.f;
  for (int i = threadIdx.x; i < V; i += 512) {
    float x = row[i];
    if (x > m) {
      s = s * __expf(m - x) + 1.f;
      m = x;
    } else {
      s += __expf(x - m);
    }
  }
#pragma unroll
  for (int off = 1; off < 64; off <<= 1) {
    float om = __shfl_xor(m, off);
    float os = __shfl_xor(s, off);
    float M = fmaxf(m, om);
    s = s * __expf(m - M) + os * __expf(om - M);
    m = M;
  }
  __shared__ float sm[8], ss[8];
  int w = threadIdx.x >> 6;
  if ((threadIdx.x & 63) == 0) { sm[w] = m; ss[w] = s; }
  __syncthreads();
  if (threadIdx.x == 0) {
    m = sm[0]; s = ss[0];
    for (int i = 1; i < 8; ++i) {
      float M = fmaxf(m, sm[i]);
      s = s * __expf(m - M) + ss[i] * __expf(sm[i] - M);
      m = M;
    }
    logZ[r] = m + __logf(s);
  }
}

__global__ __launch_bounds__(256) void k_sub(float* __restrict__ o, const float* __restrict__ logZ) {
  int r = blockIdx.y;
  int i = blockIdx.x * 256 + threadIdx.x;
  if (i < V) o[(long)r * V + i] -= logZ[r];
}

}  // namespace

extern "C" void kernel_launch(void* const* d_in, const int* in_sizes, int n_in,
                              void* d_out, int out_size, void* d_ws, size_t ws_size,
                              hipStream_t stream) {
  const int* inp = (const int*)d_in[0];
  const float* h0 = (const float*)d_in[1];
  const float* c0 = (const float*)d_in[2];
  const float* kk = (const float*)d_in[3];
  // d_in[4] = context_vector (unused by reference)
  const float* emb = (const float*)d_in[5];
  const float* W_ih = (const float*)d_in[6];
  const float* b_ih = (const float*)d_in[7];
  const float* W_hh = (const float*)d_in[8];
  const float* b_hh = (const float*)d_in[9];
  const float* W1 = (const float*)d_in[10];
  const float* b1 = (const float*)d_in[11];
  const float* W2 = (const float*)d_in[12];
  const float* b2 = (const float*)d_in[13];
  const float* W3 = (const float*)d_in[14];
  const float* b3 = (const float*)d_in[15];
  const float* W_out = (const float*)d_in[16];
  const float* b_out = (const float*)d_in[17];

  float* y = (float*)d_out;                 // B*V
  float* h_t = y + (size_t)B * V;           // B*H
  float* c_t = h_t + (size_t)B * H;         // B*H

  char* ws = (char*)d_ws;
  float* gates = (float*)ws;                 ws += (size_t)4 * H * B * 4;      // 512 KB
  float* Ah = (float*)ws;                    ws += (size_t)B * E * 4;          // 64 KB
  float* Kp = (float*)ws;                    ws += (size_t)KV * E * 4;         // 2 MB
  float* scores = (float*)ws;                ws += (size_t)B * KV * 4;         // 512 KB
  float* logZ = (float*)ws;                  ws += 256;
  __bf16* W2p = (__bf16*)ws;                 ws += (size_t)E * E * 2;          // 128 KB
  __bf16* hp = (__bf16*)ws;                  ws += (size_t)B * H * 2;          // 64 KB

  hipLaunchKernelGGL(k_gates, dim3(4 * H / 4), dim3(256), 0, stream,
                     inp, h0, emb, W_ih, b_ih, W_hh, b_hh, gates);
  hipLaunchKernelGGL(k_lstm, dim3(B * H / 256), dim3(256), 0, stream, gates, c0, h_t, c_t);
  hipLaunchKernelGGL(k_ah, dim3(E / 4), dim3(256), 0, stream, h_t, W1, b1, Ah);
  hipLaunchKernelGGL(k_kp, dim3(KV / 64, E / 64), dim3(256), 0, stream, kk, W1, Kp);
  hipLaunchKernelGGL(k_packw2, dim3(E * E / 256), dim3(256), 0, stream, W2, W2p);
  hipLaunchKernelGGL(k_packh, dim3(B * H / 256), dim3(256), 0, stream, h_t, hp);
  hipLaunchKernelGGL(k_attn, dim3(B * KV / 64), dim3(256), 0, stream,
                     Ah, Kp, W2p, b2, W3, b3, scores);
  hipLaunchKernelGGL(k_out, dim3((V + 63) / 64), dim3(256), 0, stream,
                     hp, W_out, b_out, scores, y);
  hipLaunchKernelGGL(k_lse, dim3(B), dim3(512), 0, stream, y, logZ);
  hipLaunchKernelGGL(k_sub, dim3((V + 255) / 256, B), dim3(256), 0, stream, y, logZ);
}

// Round 2
// 169.832 us; speedup vs baseline: 1.3276x; 1.3276x over previous
//
#include <hip/hip_runtime.h>
#include <math.h>

namespace {

constexpr int B = 64, E = 256, H = 512, V = 50257, KV = 2048;
constexpr int NOUT = (V + 63) / 64;   // 786 k_out blocks
constexpr int PSTRIDE = 800;          // padded partial stride

typedef __bf16 bf16x8 __attribute__((ext_vector_type(8)));
typedef float f32x4 __attribute__((ext_vector_type(4)));

__device__ __forceinline__ float fast_tanh(float x) {
  float e = __expf(2.f * x);
  return 1.f - 2.f / (e + 1.f);
}
__device__ __forceinline__ float sigmoidf(float x) {
  return 1.f / (1.f + __expf(-x));
}
__device__ __forceinline__ f32x4 mfma16(bf16x8 a, bf16x8 b, f32x4 c) {
  return __builtin_amdgcn_mfma_f32_16x16x32_bf16(a, b, c, 0, 0, 0);
}

// ---------------- LSTM gates: gates[j][b] = b_ih[j]+b_hh[j] + x[b].W_ih[j] + h0[b].W_hh[j]
__global__ __launch_bounds__(256) void k_gates(const int* __restrict__ inp,
    const float* __restrict__ h0, const float* __restrict__ emb,
    const float* __restrict__ W_ih, const float* __restrict__ b_ih,
    const float* __restrict__ W_hh, const float* __restrict__ b_hh,
    float* __restrict__ gates) {
  int b = threadIdx.x & 63;
  int j = blockIdx.x * 4 + (threadIdx.x >> 6);
  j = __builtin_amdgcn_readfirstlane(j);
  int row = inp[b];
  const float* xr = emb + (long)row * E;
  const float* wi = W_ih + (long)j * E;
  const float* hr = h0 + b * H;
  const float* wh = W_hh + (long)j * H;
  float acc = b_ih[j] + b_hh[j];
#pragma unroll 8
  for (int t = 0; t < E / 4; ++t) {
    float4 x4 = ((const float4*)xr)[t];
    float4 w4 = ((const float4*)wi)[t];
    acc += x4.x * w4.x + x4.y * w4.y + x4.z * w4.z + x4.w * w4.w;
  }
#pragma unroll 8
  for (int t = 0; t < H / 4; ++t) {
    float4 h4 = ((const float4*)hr)[t];
    float4 w4 = ((const float4*)wh)[t];
    acc += h4.x * w4.x + h4.y * w4.y + h4.z * w4.z + h4.w * w4.w;
  }
  gates[j * B + b] = acc;
}

// ---------------- LSTM elementwise: h_t, c_t, + bf16 packed h (MFMA A-fragment layout)
__global__ __launch_bounds__(256) void k_lstm(const float* __restrict__ gates,
    const float* __restrict__ c0, float* __restrict__ out_h, float* __restrict__ out_c,
    __bf16* __restrict__ hp) {
  int i = blockIdx.x * 256 + threadIdx.x;  // 32768 = B*H
  int b = i >> 9, hh = i & 511;
  float gi = gates[(hh)*B + b];
  float gf = gates[(hh + 512) * B + b];
  float gg = gates[(hh + 1024) * B + b];
  float go = gates[(hh + 1536) * B + b];
  float c = sigmoidf(gf) * c0[i] + sigmoidf(gi) * fast_tanh(gg);
  float h = sigmoidf(go) * fast_tanh(c);
  out_h[i] = h;
  out_c[i] = c;
  hp[((hh >> 3) * 64 + b) * 8 + (hh & 7)] = (__bf16)h;
}

// ---------------- prep: Ah (blocks 0..63) | Kp (blocks 64..191) | packW2 (blocks 192..447)
__global__ __launch_bounds__(256) void k_prep(const float* __restrict__ h_t,
    const float* __restrict__ W1, const float* __restrict__ b1,
    const float* __restrict__ k, const float* __restrict__ W2,
    float* __restrict__ Ah, float* __restrict__ Kp, __bf16* __restrict__ W2p) {
  __shared__ float ks_[64][257];
  int bid = blockIdx.x;
  int t = threadIdx.x;
  if (bid < 64) {
    // Ah[b][e] = b1[e] + h_t[b] . W1[e][0:512]
    int b = t & 63;
    int e = bid * 4 + (t >> 6);
    e = __builtin_amdgcn_readfirstlane(e);
    const float* hr = h_t + b * H;
    const float* wr = W1 + (long)e * (E + H);
    float acc = b1[e];
#pragma unroll 8
    for (int q = 0; q < H / 4; ++q) {
      float4 h4 = ((const float4*)hr)[q];
      float4 w4 = ((const float4*)wr)[q];
      acc += h4.x * w4.x + h4.y * w4.y + h4.z * w4.z + h4.w * w4.w;
    }
    Ah[b * E + e] = acc;
  } else if (bid < 192) {
    // Kp[kv][e] = k[kv] . W1[e][512:768]
    int t2 = bid - 64;
    int kv0 = (t2 & 31) * 64;
    int e0 = (t2 >> 5) * 64;
    for (int i = 0; i < 16; ++i) {
      int idx = i * 256 + t;
      int rr = idx >> 6, cc = (idx & 63) * 4;
      float4 v = *(const float4*)(k + (kv0 + rr) * E + cc);
      ks_[rr][cc] = v.x; ks_[rr][cc + 1] = v.y; ks_[rr][cc + 2] = v.z; ks_[rr][cc + 3] = v.w;
    }
    __syncthreads();
    int r0 = (t >> 4);
    int c0 = (t & 15) * 4;
    float acc[4][4] = {};
    const float* w0 = W1 + (long)(e0 + c0) * (E + H) + H;
    for (int kk = 0; kk < 256; kk += 4) {
      float4 w[4];
#pragma unroll
      for (int c = 0; c < 4; ++c) w[c] = *(const float4*)(w0 + (long)c * (E + H) + kk);
#pragma unroll
      for (int q = 0; q < 4; ++q) {
#pragma unroll
        for (int r = 0; r < 4; ++r) {
          float kvv = ks_[r0 + 16 * r][kk + q];
#pragma unroll
          for (int c = 0; c < 4; ++c) acc[r][c] += kvv * ((const float*)&w[c])[q];
        }
      }
    }
    for (int r = 0; r < 4; ++r)
      for (int c = 0; c < 4; ++c)
        Kp[(kv0 + r0 + 16 * r) * E + e0 + c0 + c] = acc[r][c];
  } else {
    // pack W2^T -> bf16 MFMA-B-fragment layout
    int idx = (bid - 192) * 256 + t;  // 65536
    int kk = idx >> 8, n = idx & 255;
    W2p[((kk >> 3) * 256 + n) * 8 + (kk & 7)] = (__bf16)W2[n * 256 + kk];
  }
}

// ---------------- attention core: per block 64 kv rows for one b.
__global__ __launch_bounds__(256) void k_attn(const float* __restrict__ Ah,
    const float* __restrict__ Kp, const __bf16* __restrict__ W2p,
    const float* __restrict__ b2, const float* __restrict__ W3, const float* __restrict__ b3,
    float* __restrict__ scoresT) {
  __shared__ __align__(16) unsigned char lds_[64 * 256 * 2];
  int tid = threadIdx.x;
  int blk = blockIdx.x;             // 2048
  int b = blk >> 5;
  int kv0 = (blk & 31) * 64;
  for (int i = 0; i < 8; ++i) {
    int idx = i * 256 + tid;
    int row = idx >> 5;
    int k0 = (idx & 31) * 8;
    const float* ap = Ah + b * E + k0;
    const float* kp = Kp + (kv0 + row) * E + k0;
    float4 a0 = *(const float4*)ap;
    float4 a1 = *(const float4*)(ap + 4);
    float4 p0 = *(const float4*)kp;
    float4 p1 = *(const float4*)(kp + 4);
    bf16x8 u;
    u[0] = (__bf16)fast_tanh(a0.x + p0.x);
    u[1] = (__bf16)fast_tanh(a0.y + p0.y);
    u[2] = (__bf16)fast_tanh(a0.z + p0.z);
    u[3] = (__bf16)fast_tanh(a0.w + p0.w);
    u[4] = (__bf16)fast_tanh(a1.x + p1.x);
    u[5] = (__bf16)fast_tanh(a1.y + p1.y);
    u[6] = (__bf16)fast_tanh(a1.z + p1.z);
    u[7] = (__bf16)fast_tanh(a1.w + p1.w);
    int byte = (row * 512 + k0 * 2) ^ ((row & 7) << 4);
    *(bf16x8*)(lds_ + byte) = u;
  }
  __syncthreads();
  int l = tid & 63, wc = tid >> 6;
  int lr = l & 15, lg = l >> 4;
  float b2v[4], w3v[4];
#pragma unroll
  for (int nf = 0; nf < 4; ++nf) {
    int col = wc * 64 + nf * 16 + lr;
    b2v[nf] = b2[col];
    w3v[nf] = W3[col];
  }
  f32x4 acc[4][4] = {};
  for (int ks = 0; ks < 8; ++ks) {
    bf16x8 a[4], bf[4];
#pragma unroll
    for (int mf = 0; mf < 4; ++mf) {
      int row = mf * 16 + lr;
      int byte = (row * 512 + (ks * 32 + lg * 8) * 2) ^ ((row & 7) << 4);
      a[mf] = *(const bf16x8*)(lds_ + byte);
    }
#pragma unroll
    for (int nf = 0; nf < 4; ++nf) {
      int col = wc * 64 + nf * 16 + lr;
      bf[nf] = *(const bf16x8*)(W2p + ((ks * 4 + lg) * 256 + col) * 8);
    }
#pragma unroll
    for (int mf = 0; mf < 4; ++mf)
#pragma unroll
      for (int nf = 0; nf < 4; ++nf)
        acc[mf][nf] = mfma16(a[mf], bf[nf], acc[mf][nf]);
  }
  float p[4][4];
#pragma unroll
  for (int mf = 0; mf < 4; ++mf)
#pragma unroll
    for (int r = 0; r < 4; ++r) p[mf][r] = 0.f;
#pragma unroll
  for (int mf = 0; mf < 4; ++mf)
#pragma unroll
    for (int nf = 0; nf < 4; ++nf)
#pragma unroll
      for (int r = 0; r < 4; ++r) {
        float u2 = fast_tanh(acc[mf][nf][r] + b2v[nf]);
        p[mf][r] += u2 * w3v[nf];
      }
#pragma unroll
  for (int off = 1; off < 16; off <<= 1)
#pragma unroll
    for (int mf = 0; mf < 4; ++mf)
#pragma unroll
      for (int r = 0; r < 4; ++r) p[mf][r] += __shfl_xor(p[mf][r], off);
  __syncthreads();
  float* red = (float*)lds_;  // [64][4]
  if (lr == 0) {
#pragma unroll
    for (int mf = 0; mf < 4; ++mf)
#pragma unroll
      for (int r = 0; r < 4; ++r) red[(mf * 16 + lg * 4 + r) * 4 + wc] = p[mf][r];
  }
  __syncthreads();
  if (tid < 64) {
    float s = red[tid * 4 + 0] + red[tid * 4 + 1] + red[tid * 4 + 2] + red[tid * 4 + 3] + b3[0];
    scoresT[(kv0 + tid) * 64 + b] = s;  // transposed for k_out
  }
}

// ---------------- output projection + fused per-block partial LSE
__global__ __launch_bounds__(256) void k_out(const __bf16* __restrict__ hp,
    const float* __restrict__ W_out, const float* __restrict__ b_out,
    const float* __restrict__ scoresT, float* __restrict__ o,
    float* __restrict__ pm, float* __restrict__ ps) {
  __shared__ float vbuf[64][65];
  __shared__ float rm[64][4], rs[64][4];
  int tid = threadIdx.x;
  int l = tid & 63, wn = tid >> 6;
  int lr = l & 15, lg = l >> 4;
  int col = blockIdx.x * 64 + wn * 16 + lr;
  int colc = col < V ? col : V - 1;
  const float* wr = W_out + (long)colc * H;
  f32x4 acc[4] = {};
  for (int ks = 0; ks < 16; ++ks) {
    bf16x8 a[4];
#pragma unroll
    for (int mf = 0; mf < 4; ++mf)
      a[mf] = *(const bf16x8*)(hp + ((ks * 4 + lg) * 64 + mf * 16 + lr) * 8);
    const float* wp = wr + ks * 32 + lg * 8;
    float4 w0 = *(const float4*)wp;
    float4 w1 = *(const float4*)(wp + 4);
    bf16x8 bf;
    bf[0] = (__bf16)w0.x; bf[1] = (__bf16)w0.y; bf[2] = (__bf16)w0.z; bf[3] = (__bf16)w0.w;
    bf[4] = (__bf16)w1.x; bf[5] = (__bf16)w1.y; bf[6] = (__bf16)w1.z; bf[7] = (__bf16)w1.w;
#pragma unroll
    for (int mf = 0; mf < 4; ++mf) acc[mf] = mfma16(a[mf], bf, acc[mf]);
  }
  bool valid = col < V;
  float bo = valid ? b_out[col] : 0.f;
  bool has = valid && col >= (V - KV);
  int scix = col - (V - KV);
#pragma unroll
  for (int mf = 0; mf < 4; ++mf)
#pragma unroll
    for (int r = 0; r < 4; ++r) {
      int m = mf * 16 + lg * 4 + r;
      float v = acc[mf][r] + bo;
      if (has) v += scoresT[scix * 64 + m];
      if (valid) o[(long)m * V + col] = v; else v = -1e30f;
      vbuf[m][wn * 16 + lr] = v;
    }
  __syncthreads();
  // per-row reduce over this block's 64 cols: 4 groups of 16 cols each
  int row = tid & 63, g = tid >> 6;
  float mm = -1e30f;
#pragma unroll
  for (int c = 0; c < 16; ++c) mm = fmaxf(mm, vbuf[row][g * 16 + c]);
  float ssum = 0.f;
#pragma unroll
  for (int c = 0; c < 16; ++c) ssum += __expf(vbuf[row][g * 16 + c] - mm);
  rm[row][g] = mm; rs[row][g] = ssum;
  __syncthreads();
  if (tid < 64) {
    float M = fmaxf(fmaxf(rm[tid][0], rm[tid][1]), fmaxf(rm[tid][2], rm[tid][3]));
    float S = 0.f;
#pragma unroll
    for (int g2 = 0; g2 < 4; ++g2) S += rs[tid][g2] * __expf(rm[tid][g2] - M);
    pm[tid * PSTRIDE + blockIdx.x] = M;
    ps[tid * PSTRIDE + blockIdx.x] = S;
  }
}

// ---------------- combine per-block partials -> logZ per row
__global__ __launch_bounds__(256) void k_z(const float* __restrict__ pm,
    const float* __restrict__ ps, float* __restrict__ logZ) {
  int r = blockIdx.x;
  int tid = threadIdx.x;
  float m = -1e30f, s = 0.f;
  for (int p = tid; p < NOUT; p += 256) {
    float om = pm[r * PSTRIDE + p];
    float os = ps[r * PSTRIDE + p];
    float M = fmaxf(m, om);
    s = s * __expf(m - M) + os * __expf(om - M);
    m = M;
  }
#pragma unroll
  for (int off = 1; off < 64; off <<= 1) {
    float om = __shfl_xor(m, off);
    float os = __shfl_xor(s, off);
    float M = fmaxf(m, om);
    s = s * __expf(m - M) + os * __expf(om - M);
    m = M;
  }
  __shared__ float sm[4], ss[4];
  int w = tid >> 6;
  if ((tid & 63) == 0) { sm[w] = m; ss[w] = s; }
  __syncthreads();
  if (tid == 0) {
    m = sm[0]; s = ss[0];
    for (int i = 1; i < 4; ++i) {
      float M = fmaxf(m, sm[i]);
      s = s * __expf(m - M) + ss[i] * __expf(sm[i] - M);
      m = M;
    }
    logZ[r] = m + __logf(s);
  }
}

// ---------------- subtract logZ (float4)
__global__ __launch_bounds__(256) void k_sub(float* __restrict__ o, const float* __restrict__ logZ) {
  int r = blockIdx.y;
  float z = logZ[r];
  int i0 = (blockIdx.x * 256 + threadIdx.x) * 4;
  float* row = o + (long)r * V;
  if (i0 + 3 < V) {
    float4 v = *(float4*)(row + i0);
    v.x -= z; v.y -= z; v.z -= z; v.w -= z;
    *(float4*)(row + i0) = v;
  } else {
    for (int i = i0; i < V; ++i) row[i] -= z;
  }
}

}  // namespace

extern "C" void kernel_launch(void* const* d_in, const int* in_sizes, int n_in,
                              void* d_out, int out_size, void* d_ws, size_t ws_size,
                              hipStream_t stream) {
  const int* inp = (const int*)d_in[0];
  const float* h0 = (const float*)d_in[1];
  const float* c0 = (const float*)d_in[2];
  const float* kk = (const float*)d_in[3];
  const float* emb = (const float*)d_in[5];
  const float* W_ih = (const float*)d_in[6];
  const float* b_ih = (const float*)d_in[7];
  const float* W_hh = (const float*)d_in[8];
  const float* b_hh = (const float*)d_in[9];
  const float* W1 = (const float*)d_in[10];
  const float* b1 = (const float*)d_in[11];
  const float* W2 = (const float*)d_in[12];
  const float* b2 = (const float*)d_in[13];
  const float* W3 = (const float*)d_in[14];
  const float* b3 = (const float*)d_in[15];
  const float* W_out = (const float*)d_in[16];
  const float* b_out = (const float*)d_in[17];

  float* y = (float*)d_out;                 // B*V
  float* h_t = y + (size_t)B * V;           // B*H
  float* c_t = h_t + (size_t)B * H;         // B*H

  char* ws = (char*)d_ws;
  float* gates = (float*)ws;                 ws += (size_t)4 * H * B * 4;
  float* Ah = (float*)ws;                    ws += (size_t)B * E * 4;
  float* Kp = (float*)ws;                    ws += (size_t)KV * E * 4;
  float* scoresT = (float*)ws;               ws += (size_t)B * KV * 4;
  float* logZ = (float*)ws;                  ws += 256;
  float* pm = (float*)ws;                    ws += (size_t)B * PSTRIDE * 4;
  float* ps = (float*)ws;                    ws += (size_t)B * PSTRIDE * 4;
  __bf16* W2p = (__bf16*)ws;                 ws += (size_t)E * E * 2;
  __bf16* hp = (__bf16*)ws;                  ws += (size_t)B * H * 2;

  hipLaunchKernelGGL(k_gates, dim3(4 * H / 4), dim3(256), 0, stream,
                     inp, h0, emb, W_ih, b_ih, W_hh, b_hh, gates);
  hipLaunchKernelGGL(k_lstm, dim3(B * H / 256), dim3(256), 0, stream, gates, c0, h_t, c_t, hp);
  hipLaunchKernelGGL(k_prep, dim3(448), dim3(256), 0, stream,
                     h_t, W1, b1, kk, W2, Ah, Kp, W2p);
  hipLaunchKernelGGL(k_attn, dim3(B * KV / 64), dim3(256), 0, stream,
                     Ah, Kp, W2p, b2, W3, b3, scoresT);
  hipLaunchKernelGGL(k_out, dim3(NOUT), dim3(256), 0, stream,
                     hp, W_out, b_out, scoresT, y, pm, ps);
  hipLaunchKernelGGL(k_z, dim3(B), dim3(256), 0, stream, pm, ps, logZ);
  hipLaunchKernelGGL(k_sub, dim3((V + 1023) / 1024, B), dim3(256), 0, stream, y, logZ);
}

// Round 3
// 166.733 us; speedup vs baseline: 1.3523x; 1.0186x over previous
//
#include <hip/hip_runtime.h>
#include <math.h>

namespace {

constexpr int B = 64, E = 256, H = 512, V = 50257, KV = 2048;
constexpr int NOUT = (V + 63) / 64;   // 786 k_out blocks
constexpr int PSTRIDE = 800;          // padded partial stride

typedef __bf16 bf16x8 __attribute__((ext_vector_type(8)));
typedef float f32x4 __attribute__((ext_vector_type(4)));

__device__ __forceinline__ float fast_tanh(float x) {
  float e = __expf(2.f * x);
  return 1.f - 2.f / (e + 1.f);
}
__device__ __forceinline__ float sigmoidf(float x) {
  return 1.f / (1.f + __expf(-x));
}
__device__ __forceinline__ f32x4 mfma16(bf16x8 a, bf16x8 b, f32x4 c) {
  return __builtin_amdgcn_mfma_f32_16x16x32_bf16(a, b, c, 0, 0, 0);
}

// ---------------- LSTM gates: gates[j][b] = b_ih[j]+b_hh[j] + x[b].W_ih[j] + h0[b].W_hh[j]
__global__ __launch_bounds__(256) void k_gates(const int* __restrict__ inp,
    const float* __restrict__ h0, const float* __restrict__ emb,
    const float* __restrict__ W_ih, const float* __restrict__ b_ih,
    const float* __restrict__ W_hh, const float* __restrict__ b_hh,
    float* __restrict__ gates) {
  int b = threadIdx.x & 63;
  int j = blockIdx.x * 4 + (threadIdx.x >> 6);
  j = __builtin_amdgcn_readfirstlane(j);
  int row = inp[b];
  const float* xr = emb + (long)row * E;
  const float* wi = W_ih + (long)j * E;
  const float* hr = h0 + b * H;
  const float* wh = W_hh + (long)j * H;
  float acc = b_ih[j] + b_hh[j];
#pragma unroll 8
  for (int t = 0; t < E / 4; ++t) {
    float4 x4 = ((const float4*)xr)[t];
    float4 w4 = ((const float4*)wi)[t];
    acc += x4.x * w4.x + x4.y * w4.y + x4.z * w4.z + x4.w * w4.w;
  }
#pragma unroll 8
  for (int t = 0; t < H / 4; ++t) {
    float4 h4 = ((const float4*)hr)[t];
    float4 w4 = ((const float4*)wh)[t];
    acc += h4.x * w4.x + h4.y * w4.y + h4.z * w4.z + h4.w * w4.w;
  }
  gates[j * B + b] = acc;
}

// ---------------- LSTM elementwise: h_t, c_t, + bf16 packed h (MFMA A-fragment layout)
__global__ __launch_bounds__(256) void k_lstm(const float* __restrict__ gates,
    const float* __restrict__ c0, float* __restrict__ out_h, float* __restrict__ out_c,
    __bf16* __restrict__ hp) {
  int i = blockIdx.x * 256 + threadIdx.x;  // 32768 = B*H
  int b = i >> 9, hh = i & 511;
  float gi = gates[(hh)*B + b];
  float gf = gates[(hh + 512) * B + b];
  float gg = gates[(hh + 1024) * B + b];
  float go = gates[(hh + 1536) * B + b];
  float c = sigmoidf(gf) * c0[i] + sigmoidf(gi) * fast_tanh(gg);
  float h = sigmoidf(go) * fast_tanh(c);
  out_h[i] = h;
  out_c[i] = c;
  hp[((hh >> 3) * 64 + b) * 8 + (hh & 7)] = (__bf16)h;
}

// ---------------- prep: Ah (blocks 0..63) | Kp (blocks 64..191) | packW2 (blocks 192..447)
__global__ __launch_bounds__(256) void k_prep(const float* __restrict__ h_t,
    const float* __restrict__ W1, const float* __restrict__ b1,
    const float* __restrict__ k, const float* __restrict__ W2,
    float* __restrict__ Ah, float* __restrict__ Kp, __bf16* __restrict__ W2p) {
  __shared__ float ks_[64][257];
  int bid = blockIdx.x;
  int t = threadIdx.x;
  if (bid < 64) {
    int b = t & 63;
    int e = bid * 4 + (t >> 6);
    e = __builtin_amdgcn_readfirstlane(e);
    const float* hr = h_t + b * H;
    const float* wr = W1 + (long)e * (E + H);
    float acc = b1[e];
#pragma unroll 8
    for (int q = 0; q < H / 4; ++q) {
      float4 h4 = ((const float4*)hr)[q];
      float4 w4 = ((const float4*)wr)[q];
      acc += h4.x * w4.x + h4.y * w4.y + h4.z * w4.z + h4.w * w4.w;
    }
    Ah[b * E + e] = acc;
  } else if (bid < 192) {
    int t2 = bid - 64;
    int kv0 = (t2 & 31) * 64;
    int e0 = (t2 >> 5) * 64;
    for (int i = 0; i < 16; ++i) {
      int idx = i * 256 + t;
      int rr = idx >> 6, cc = (idx & 63) * 4;
      float4 v = *(const float4*)(k + (kv0 + rr) * E + cc);
      ks_[rr][cc] = v.x; ks_[rr][cc + 1] = v.y; ks_[rr][cc + 2] = v.z; ks_[rr][cc + 3] = v.w;
    }
    __syncthreads();
    int r0 = (t >> 4);
    int c0 = (t & 15) * 4;
    float acc[4][4] = {};
    const float* w0 = W1 + (long)(e0 + c0) * (E + H) + H;
    for (int kk = 0; kk < 256; kk += 4) {
      float4 w[4];
#pragma unroll
      for (int c = 0; c < 4; ++c) w[c] = *(const float4*)(w0 + (long)c * (E + H) + kk);
#pragma unroll
      for (int q = 0; q < 4; ++q) {
#pragma unroll
        for (int r = 0; r < 4; ++r) {
          float kvv = ks_[r0 + 16 * r][kk + q];
#pragma unroll
          for (int c = 0; c < 4; ++c) acc[r][c] += kvv * ((const float*)&w[c])[q];
        }
      }
    }
    for (int r = 0; r < 4; ++r)
      for (int c = 0; c < 4; ++c)
        Kp[(kv0 + r0 + 16 * r) * E + e0 + c0 + c] = acc[r][c];
  } else {
    int idx = (bid - 192) * 256 + t;  // 65536
    int kk = idx >> 8, n = idx & 255;
    W2p[((kk >> 3) * 256 + n) * 8 + (kk & 7)] = (__bf16)W2[n * 256 + kk];
  }
}

// ---------------- attention core: per block 64 kv rows for one b.
__global__ __launch_bounds__(256) void k_attn(const float* __restrict__ Ah,
    const float* __restrict__ Kp, const __bf16* __restrict__ W2p,
    const float* __restrict__ b2, const float* __restrict__ W3, const float* __restrict__ b3,
    float* __restrict__ scoresT) {
  __shared__ __align__(16) unsigned char lds_[64 * 256 * 2];
  int tid = threadIdx.x;
  int blk = blockIdx.x;             // 2048
  int b = blk >> 5;
  int kv0 = (blk & 31) * 64;
  for (int i = 0; i < 8; ++i) {
    int idx = i * 256 + tid;
    int row = idx >> 5;
    int k0 = (idx & 31) * 8;
    const float* ap = Ah + b * E + k0;
    const float* kp = Kp + (kv0 + row) * E + k0;
    float4 a0 = *(const float4*)ap;
    float4 a1 = *(const float4*)(ap + 4);
    float4 p0 = *(const float4*)kp;
    float4 p1 = *(const float4*)(kp + 4);
    bf16x8 u;
    u[0] = (__bf16)fast_tanh(a0.x + p0.x);
    u[1] = (__bf16)fast_tanh(a0.y + p0.y);
    u[2] = (__bf16)fast_tanh(a0.z + p0.z);
    u[3] = (__bf16)fast_tanh(a0.w + p0.w);
    u[4] = (__bf16)fast_tanh(a1.x + p1.x);
    u[5] = (__bf16)fast_tanh(a1.y + p1.y);
    u[6] = (__bf16)fast_tanh(a1.z + p1.z);
    u[7] = (__bf16)fast_tanh(a1.w + p1.w);
    int byte = (row * 512 + k0 * 2) ^ ((row & 7) << 4);
    *(bf16x8*)(lds_ + byte) = u;
  }
  __syncthreads();
  int l = tid & 63, wc = tid >> 6;
  int lr = l & 15, lg = l >> 4;
  float b2v[4], w3v[4];
#pragma unroll
  for (int nf = 0; nf < 4; ++nf) {
    int col = wc * 64 + nf * 16 + lr;
    b2v[nf] = b2[col];
    w3v[nf] = W3[col];
  }
  f32x4 acc[4][4] = {};
  for (int ks = 0; ks < 8; ++ks) {
    bf16x8 a[4], bf[4];
#pragma unroll
    for (int mf = 0; mf < 4; ++mf) {
      int row = mf * 16 + lr;
      int byte = (row * 512 + (ks * 32 + lg * 8) * 2) ^ ((row & 7) << 4);
      a[mf] = *(const bf16x8*)(lds_ + byte);
    }
#pragma unroll
    for (int nf = 0; nf < 4; ++nf) {
      int col = wc * 64 + nf * 16 + lr;
      bf[nf] = *(const bf16x8*)(W2p + ((ks * 4 + lg) * 256 + col) * 8);
    }
#pragma unroll
    for (int mf = 0; mf < 4; ++mf)
#pragma unroll
      for (int nf = 0; nf < 4; ++nf)
        acc[mf][nf] = mfma16(a[mf], bf[nf], acc[mf][nf]);
  }
  float p[4][4];
#pragma unroll
  for (int mf = 0; mf < 4; ++mf)
#pragma unroll
    for (int r = 0; r < 4; ++r) p[mf][r] = 0.f;
#pragma unroll
  for (int mf = 0; mf < 4; ++mf)
#pragma unroll
    for (int nf = 0; nf < 4; ++nf)
#pragma unroll
      for (int r = 0; r < 4; ++r) {
        float u2 = fast_tanh(acc[mf][nf][r] + b2v[nf]);
        p[mf][r] += u2 * w3v[nf];
      }
#pragma unroll
  for (int off = 1; off < 16; off <<= 1)
#pragma unroll
    for (int mf = 0; mf < 4; ++mf)
#pragma unroll
      for (int r = 0; r < 4; ++r) p[mf][r] += __shfl_xor(p[mf][r], off);
  __syncthreads();
  float* red = (float*)lds_;  // [64][4]
  if (lr == 0) {
#pragma unroll
    for (int mf = 0; mf < 4; ++mf)
#pragma unroll
      for (int r = 0; r < 4; ++r) red[(mf * 16 + lg * 4 + r) * 4 + wc] = p[mf][r];
  }
  __syncthreads();
  if (tid < 64) {
    float s = red[tid * 4 + 0] + red[tid * 4 + 1] + red[tid * 4 + 2] + red[tid * 4 + 3] + b3[0];
    scoresT[(kv0 + tid) * 64 + b] = s;  // transposed for k_out
  }
}

// ---------------- output projection + fused per-block partial LSE
// Coalesced: stage W_out tile (64 cols x 512 K) through LDS in two 256-K
// halves (bf16, XOR-swizzled), MFMA from LDS. 34 KB LDS -> 4 blocks/CU.
__global__ __launch_bounds__(256) void k_out(const __bf16* __restrict__ hp,
    const float* __restrict__ W_out, const float* __restrict__ b_out,
    const float* __restrict__ scoresT, float* __restrict__ o,
    float* __restrict__ pm, float* __restrict__ ps) {
  __shared__ __align__(16) unsigned char lds_[64 * 256 * 2];  // 32 KB half-tile
  __shared__ float rm[64][4], rs[64][4];
  int tid = threadIdx.x;
  int l = tid & 63, wn = tid >> 6;
  int lr = l & 15, lg = l >> 4;
  int col0 = blockIdx.x * 64;
  f32x4 acc[4] = {};
#pragma unroll
  for (int hh = 0; hh < 2; ++hh) {
    if (hh) __syncthreads();  // protect LDS before overwrite (after half-0 MFMA)
    // stage: 64 rows x 256 K fp32 -> bf16 LDS, coalesced 32 B/thread/iter
#pragma unroll
    for (int i = 0; i < 8; ++i) {
      int u = i * 256 + tid;          // 2048 16B-units: [64 rows][32 units]
      int row = u >> 5;
      int c16 = u & 31;
      int rr = col0 + row; if (rr > V - 1) rr = V - 1;
      const float* p = W_out + (long)rr * H + hh * 256 + c16 * 8;
      float4 w0 = *(const float4*)p;
      float4 w1 = *(const float4*)(p + 4);
      bf16x8 v;
      v[0] = (__bf16)w0.x; v[1] = (__bf16)w0.y; v[2] = (__bf16)w0.z; v[3] = (__bf16)w0.w;
      v[4] = (__bf16)w1.x; v[5] = (__bf16)w1.y; v[6] = (__bf16)w1.z; v[7] = (__bf16)w1.w;
      int byte = (row * 512 + c16 * 16) ^ ((row & 7) << 4);
      *(bf16x8*)(lds_ + byte) = v;
    }
    __syncthreads();
    int r = wn * 16 + lr;
    int rbase = r * 512;
    int rsw = (r & 7) << 4;
#pragma unroll
    for (int ks2 = 0; ks2 < 8; ++ks2) {
      int ksg = hh * 8 + ks2;
      bf16x8 a[4];
#pragma unroll
      for (int mf = 0; mf < 4; ++mf)
        a[mf] = *(const bf16x8*)(hp + ((ksg * 4 + lg) * 64 + mf * 16 + lr) * 8);
      bf16x8 bv = *(const bf16x8*)(lds_ + ((rbase + ks2 * 64 + lg * 16) ^ rsw));
#pragma unroll
      for (int mf = 0; mf < 4; ++mf) acc[mf] = mfma16(a[mf], bv, acc[mf]);
    }
  }
  __syncthreads();
  float (*vbuf)[65] = (float(*)[65])lds_;  // alias: [64][65] = 16.6 KB
  int col = col0 + wn * 16 + lr;
  bool valid = col < V;
  float bo = valid ? b_out[col] : 0.f;
  bool has = valid && col >= (V - KV);
  int scix = col - (V - KV);
#pragma unroll
  for (int mf = 0; mf < 4; ++mf)
#pragma unroll
    for (int r = 0; r < 4; ++r) {
      int m = mf * 16 + lg * 4 + r;
      float v = acc[mf][r] + bo;
      if (has) v += scoresT[scix * 64 + m];
      if (!valid) v = -1e30f;
      vbuf[m][wn * 16 + lr] = v;
    }
  __syncthreads();
  // coalesced o-write from vbuf
  int nvalid = V - col0; if (nvalid > 64) nvalid = 64;
#pragma unroll
  for (int i = 0; i < 16; ++i) {
    int idx = i * 256 + tid;  // 4096: [64 m][64 c]
    int m = idx >> 6, c = idx & 63;
    if (c < nvalid) o[(long)m * V + col0 + c] = vbuf[m][c];
  }
  // per-row partial LSE over this block's 64 cols
  int row = tid & 63, g = tid >> 6;
  float mm = -1e30f;
#pragma unroll
  for (int c = 0; c < 16; ++c) mm = fmaxf(mm, vbuf[row][g * 16 + c]);
  float ssum = 0.f;
#pragma unroll
  for (int c = 0; c < 16; ++c) ssum += __expf(vbuf[row][g * 16 + c] - mm);
  rm[row][g] = mm; rs[row][g] = ssum;
  __syncthreads();
  if (tid < 64) {
    float M = fmaxf(fmaxf(rm[tid][0], rm[tid][1]), fmaxf(rm[tid][2], rm[tid][3]));
    float S = 0.f;
#pragma unroll
    for (int g2 = 0; g2 < 4; ++g2) S += rs[tid][g2] * __expf(rm[tid][g2] - M);
    pm[tid * PSTRIDE + blockIdx.x] = M;
    ps[tid * PSTRIDE + blockIdx.x] = S;
  }
}

// ---------------- combine per-block partials -> logZ per row
__global__ __launch_bounds__(256) void k_z(const float* __restrict__ pm,
    const float* __restrict__ ps, float* __restrict__ logZ) {
  int r = blockIdx.x;
  int tid = threadIdx.x;
  float m = -1e30f, s = 0.f;
  for (int p = tid; p < NOUT; p += 256) {
    float om = pm[r * PSTRIDE + p];
    float os = ps[r * PSTRIDE + p];
    float M = fmaxf(m, om);
    s = s * __expf(m - M) + os * __expf(om - M);
    m = M;
  }
#pragma unroll
  for (int off = 1; off < 64; off <<= 1) {
    float om = __shfl_xor(m, off);
    float os = __shfl_xor(s, off);
    float M = fmaxf(m, om);
    s = s * __expf(m - M) + os * __expf(om - M);
    m = M;
  }
  __shared__ float sm[4], ss[4];
  int w = tid >> 6;
  if ((tid & 63) == 0) { sm[w] = m; ss[w] = s; }
  __syncthreads();
  if (tid == 0) {
    m = sm[0]; s = ss[0];
    for (int i = 1; i < 4; ++i) {
      float M = fmaxf(m, sm[i]);
      s = s * __expf(m - M) + ss[i] * __expf(sm[i] - M);
      m = M;
    }
    logZ[r] = m + __logf(s);
  }
}

// ---------------- subtract logZ (float4)
__global__ __launch_bounds__(256) void k_sub(float* __restrict__ o, const float* __restrict__ logZ) {
  int r = blockIdx.y;
  float z = logZ[r];
  int i0 = (blockIdx.x * 256 + threadIdx.x) * 4;
  float* row = o + (long)r * V;
  if (i0 + 3 < V) {
    float4 v = *(float4*)(row + i0);
    v.x -= z; v.y -= z; v.z -= z; v.w -= z;
    *(float4*)(row + i0) = v;
  } else {
    for (int i = i0; i < V; ++i) row[i] -= z;
  }
}

}  // namespace

extern "C" void kernel_launch(void* const* d_in, const int* in_sizes, int n_in,
                              void* d_out, int out_size, void* d_ws, size_t ws_size,
                              hipStream_t stream) {
  const int* inp = (const int*)d_in[0];
  const float* h0 = (const float*)d_in[1];
  const float* c0 = (const float*)d_in[2];
  const float* kk = (const float*)d_in[3];
  const float* emb = (const float*)d_in[5];
  const float* W_ih = (const float*)d_in[6];
  const float* b_ih = (const float*)d_in[7];
  const float* W_hh = (const float*)d_in[8];
  const float* b_hh = (const float*)d_in[9];
  const float* W1 = (const float*)d_in[10];
  const float* b1 = (const float*)d_in[11];
  const float* W2 = (const float*)d_in[12];
  const float* b2 = (const float*)d_in[13];
  const float* W3 = (const float*)d_in[14];
  const float* b3 = (const float*)d_in[15];
  const float* W_out = (const float*)d_in[16];
  const float* b_out = (const float*)d_in[17];

  float* y = (float*)d_out;                 // B*V
  float* h_t = y + (size_t)B * V;           // B*H
  float* c_t = h_t + (size_t)B * H;         // B*H

  char* ws = (char*)d_ws;
  float* gates = (float*)ws;                 ws += (size_t)4 * H * B * 4;
  float* Ah = (float*)ws;                    ws += (size_t)B * E * 4;
  float* Kp = (float*)ws;                    ws += (size_t)KV * E * 4;
  float* scoresT = (float*)ws;               ws += (size_t)B * KV * 4;
  float* logZ = (float*)ws;                  ws += 256;
  float* pm = (float*)ws;                    ws += (size_t)B * PSTRIDE * 4;
  float* ps = (float*)ws;                    ws += (size_t)B * PSTRIDE * 4;
  __bf16* W2p = (__bf16*)ws;                 ws += (size_t)E * E * 2;
  __bf16* hp = (__bf16*)ws;                  ws += (size_t)B * H * 2;

  hipLaunchKernelGGL(k_gates, dim3(4 * H / 4), dim3(256), 0, stream,
                     inp, h0, emb, W_ih, b_ih, W_hh, b_hh, gates);
  hipLaunchKernelGGL(k_lstm, dim3(B * H / 256), dim3(256), 0, stream, gates, c0, h_t, c_t, hp);
  hipLaunchKernelGGL(k_prep, dim3(448), dim3(256), 0, stream,
                     h_t, W1, b1, kk, W2, Ah, Kp, W2p);
  hipLaunchKernelGGL(k_attn, dim3(B * KV / 64), dim3(256), 0, stream,
                     Ah, Kp, W2p, b2, W3, b3, scoresT);
  hipLaunchKernelGGL(k_out, dim3(NOUT), dim3(256), 0, stream,
                     hp, W_out, b_out, scoresT, y, pm, ps);
  hipLaunchKernelGGL(k_z, dim3(B), dim3(256), 0, stream, pm, ps, logZ);
  hipLaunchKernelGGL(k_sub, dim3((V + 1023) / 1024, B), dim3(256), 0, stream, y, logZ);
}